// Round 1
// baseline (236.134 us; speedup 1.0000x reference)
//
#include <hip/hip_runtime.h>
#include <hip/hip_bf16.h>
#include <math.h>

#define BB 8
#define TT 256
#define DD 1024
#define HH 512
#define NSPANS 32896   // T*(T+1)/2
#define KK 512
#define NEGV -1e20f

// ---------------------------------------------------------------------------
// Kernel 1: hs = X @ W_start + b_start ; he = X @ W_end + b_end
// X: [2048,1024], W: [1024,512]. 64x64 tile, 256 threads, 4x4 per thread.
// ---------------------------------------------------------------------------
__global__ __launch_bounds__(256) void gemm_proj(
    const float* __restrict__ X,
    const float* __restrict__ Ws, const float* __restrict__ bs,
    const float* __restrict__ We, const float* __restrict__ be,
    float* __restrict__ hs, float* __restrict__ he)
{
    const float* W    = blockIdx.z ? We : Ws;
    const float* bias = blockIdx.z ? be : bs;
    float*       Y    = blockIdx.z ? he : hs;

    const int m0 = blockIdx.y * 64;
    const int n0 = blockIdx.x * 64;

    __shared__ float As[16][65];   // [k][m], padded
    __shared__ float Bs[16][64];   // [k][n]

    const int tid = threadIdx.x;
    const int tx = tid & 15, ty = tid >> 4;

    float acc[4][4] = {};

    const int ka = tid & 15, ma = tid >> 4;   // A load: k fast, m slow
    const int nb = tid & 63, kb = tid >> 6;   // B load: n fast, k slow

    for (int k0 = 0; k0 < DD; k0 += 16) {
        #pragma unroll
        for (int i = 0; i < 4; ++i)
            As[ka][ma + 16*i] = X[(m0 + ma + 16*i) * DD + k0 + ka];
        #pragma unroll
        for (int i = 0; i < 4; ++i)
            Bs[kb + 4*i][nb] = W[(k0 + kb + 4*i) * HH + n0 + nb];
        __syncthreads();

        #pragma unroll
        for (int k = 0; k < 16; ++k) {
            float a[4], bb[4];
            #pragma unroll
            for (int i = 0; i < 4; ++i) a[i]  = As[k][ty*4 + i];
            #pragma unroll
            for (int j = 0; j < 4; ++j) bb[j] = Bs[k][tx*4 + j];
            #pragma unroll
            for (int i = 0; i < 4; ++i)
                #pragma unroll
                for (int j = 0; j < 4; ++j)
                    acc[i][j] += a[i] * bb[j];
        }
        __syncthreads();
    }

    #pragma unroll
    for (int i = 0; i < 4; ++i) {
        const int m = m0 + ty*4 + i;
        #pragma unroll
        for (int j = 0; j < 4; ++j) {
            const int n = n0 + tx*4 + j;
            Y[m * HH + n] = acc[i][j] + bias[n];
        }
    }
}

// ---------------------------------------------------------------------------
// Kernel 2: scores[b, triIdx(s,e)] = relu(hs[b,s,:]+he[b,e,:]) . w + b_score
// One block per (b,s); hs row + w in LDS; one wave per e.
// ---------------------------------------------------------------------------
__global__ __launch_bounds__(256) void span_scores(
    const float* __restrict__ hs, const float* __restrict__ he,
    const float* __restrict__ w_score, const float* __restrict__ b_score,
    const int* __restrict__ input_mask, float* __restrict__ scores)
{
    const int bx = blockIdx.x;
    const int b = bx >> 8;
    const int s = bx & 255;

    __shared__ float shs[HH];
    __shared__ float sw[HH];

    const int tid = threadIdx.x;
    for (int i = tid; i < HH; i += 256) {
        shs[i] = hs[(b*TT + s)*HH + i];
        sw[i]  = w_score[i];
    }
    __syncthreads();

    const int   ms  = input_mask[b*TT + s];
    const float bsc = b_score[0];
    const int wave = tid >> 6, lane = tid & 63;
    const int rowBase = s*TT - (s*(s-1))/2;

    const float4 h0 = *(const float4*)&shs[lane*8];
    const float4 h1 = *(const float4*)&shs[lane*8 + 4];
    const float4 w0 = *(const float4*)&sw[lane*8];
    const float4 w1 = *(const float4*)&sw[lane*8 + 4];

    for (int e = s + wave; e < TT; e += 4) {
        const float4* hp = (const float4*)&he[(b*TT + e)*HH];
        const float4 e0 = hp[lane*2];
        const float4 e1 = hp[lane*2 + 1];

        float p = 0.f;
        p += fmaxf(h0.x + e0.x, 0.f) * w0.x;
        p += fmaxf(h0.y + e0.y, 0.f) * w0.y;
        p += fmaxf(h0.z + e0.z, 0.f) * w0.z;
        p += fmaxf(h0.w + e0.w, 0.f) * w0.w;
        p += fmaxf(h1.x + e1.x, 0.f) * w1.x;
        p += fmaxf(h1.y + e1.y, 0.f) * w1.y;
        p += fmaxf(h1.z + e1.z, 0.f) * w1.z;
        p += fmaxf(h1.w + e1.w, 0.f) * w1.w;

        #pragma unroll
        for (int off = 32; off; off >>= 1) p += __shfl_down(p, off);

        if (lane == 0) {
            float scv = p + bsc;
            const int me = input_mask[b*TT + e];
            if (!(ms && me)) scv = NEGV;
            scores[b*NSPANS + rowBase + (e - s)] = scv;
        }
    }
}

// ---------------------------------------------------------------------------
// Kernel 3: exact top-K selection per batch (radix select on float bits),
// output indices sorted ascending, ties broken lower-index-first (jax policy).
// One block (1024 threads) per batch.
// ---------------------------------------------------------------------------
__device__ inline unsigned f2key(float f) {
    unsigned u = __float_as_uint(f);
    return u ^ ((u & 0x80000000u) ? 0xFFFFFFFFu : 0x80000000u);
}

__global__ __launch_bounds__(1024) void topk_select(
    const float* __restrict__ scores, int* __restrict__ top_idx)
{
    const int b = blockIdx.x;
    const float* sc = scores + b * NSPANS;
    const int tid = threadIdx.x;

    __shared__ unsigned hist[256];
    __shared__ unsigned sh_b[3];

    unsigned prefix = 0, remaining = KK, above = 0;

    for (int byte = 3; byte >= 0; --byte) {
        for (int i = tid; i < 256; i += 1024) hist[i] = 0;
        __syncthreads();

        const int hshift = (byte + 1) * 8;
        for (int i = tid; i < NSPANS; i += 1024) {
            const unsigned key = f2key(sc[i]);
            const bool cand = (byte == 3) ? true
                              : ((key >> hshift) == (prefix >> hshift));
            if (cand) atomicAdd(&hist[(key >> (byte*8)) & 255u], 1u);
        }
        __syncthreads();

        if (tid == 0) {
            unsigned cum = 0;
            int bin = 255;
            for (; bin > 0; --bin) {
                const unsigned h = hist[bin];
                if (cum + h >= remaining) break;
                cum += h;
            }
            sh_b[0] = prefix | ((unsigned)bin << (byte*8));
            sh_b[1] = above + cum;
            sh_b[2] = remaining - cum;
        }
        __syncthreads();
        prefix = sh_b[0]; above = sh_b[1]; remaining = sh_b[2];
        __syncthreads();
    }

    const unsigned thr = prefix;
    const unsigned tiesNeeded = remaining;

    __shared__ unsigned wSel[16], wEq[16];
    __shared__ unsigned outBase, eqBase;
    if (tid == 0) { outBase = 0; eqBase = 0; }
    __syncthreads();

    const int wave = tid >> 6, lane = tid & 63;
    const unsigned long long lmask = (1ull << lane) - 1ull;

    for (int c = 0; c < NSPANS; c += 1024) {
        const int i = c + tid;
        const bool valid = i < NSPANS;
        const unsigned key = valid ? f2key(sc[i]) : 0u;
        const bool g  = valid && (key > thr);
        const bool eq = valid && (key == thr);

        const unsigned long long me = __ballot(eq);
        if (lane == 0) wEq[wave] = (unsigned)__popcll(me);
        __syncthreads();

        unsigned wePre = 0, totE = 0;
        #pragma unroll
        for (int w = 0; w < 16; ++w) {
            const unsigned v = wEq[w];
            totE += v;
            if (w < wave) wePre += v;
        }
        const unsigned eqRank = eqBase + wePre + (unsigned)__popcll(me & lmask);
        const bool sel = g || (eq && (eqRank < tiesNeeded));

        const unsigned long long msel = __ballot(sel);
        if (lane == 0) wSel[wave] = (unsigned)__popcll(msel);
        __syncthreads();

        unsigned wsPre = 0, totS = 0;
        #pragma unroll
        for (int w = 0; w < 16; ++w) {
            const unsigned v = wSel[w];
            totS += v;
            if (w < wave) wsPre += v;
        }
        if (sel)
            top_idx[b*KK + outBase + wsPre + (unsigned)__popcll(msel & lmask)] = i;
        __syncthreads();
        if (tid == 0) { outBase += totS; eqBase += totE; }
        __syncthreads();
    }
}

// ---------------------------------------------------------------------------
// Kernel 4: gather logits, probs = sigmoid*mask, gold membership, BCE sum.
// Single block (deterministic reduction). Writes all 4097 outputs.
// ---------------------------------------------------------------------------
__global__ __launch_bounds__(1024) void finalize(
    const float* __restrict__ scores, const int* __restrict__ top_idx,
    const int* __restrict__ answer_spans, float* __restrict__ out)
{
    __shared__ int gold[BB*10];
    __shared__ float part[16];
    const int tid = threadIdx.x;

    if (tid < BB*10) {
        const int s0 = answer_spans[tid*2];
        const int e0 = answer_spans[tid*2 + 1];
        gold[tid] = (s0 >= 0) ? ((2*s0*TT - s0*s0 + s0)/2 + (e0 - s0)) : -1;
    }
    __syncthreads();

    float lsum = 0.f;
    for (int t = tid; t < BB*KK; t += 1024) {
        const int b = t >> 9, k = t & 511;
        const int idx = top_idx[b*KK + k];
        const float l = scores[b*NSPANS + idx];
        const float maskf = (l > -1e19f) ? 1.f : 0.f;
        float prob = 0.f;
        if (maskf != 0.f) {
            prob = 1.f / (1.f + expf(-l));
            float pred = 0.f;
            #pragma unroll
            for (int g = 0; g < 10; ++g)
                if (gold[b*10 + g] == idx) pred = 1.f;
            lsum += fmaxf(l, 0.f) - l*pred + log1pf(expf(-fabsf(l)));
        }
        out[t] = prob;
    }

    #pragma unroll
    for (int off = 32; off; off >>= 1) lsum += __shfl_down(lsum, off);
    const int wave = tid >> 6, lane = tid & 63;
    if (lane == 0) part[wave] = lsum;
    __syncthreads();
    if (tid == 0) {
        float ssum = 0.f;
        for (int w = 0; w < 16; ++w) ssum += part[w];
        out[BB*KK] = ssum;
    }
}

// ---------------------------------------------------------------------------
extern "C" void kernel_launch(void* const* d_in, const int* in_sizes, int n_in,
                              void* d_out, int out_size, void* d_ws, size_t ws_size,
                              hipStream_t stream)
{
    const float* inputs       = (const float*)d_in[0];
    const int*   input_mask   = (const int*)  d_in[1];
    const int*   answer_spans = (const int*)  d_in[2];
    const float* W_start      = (const float*)d_in[3];
    const float* b_start      = (const float*)d_in[4];
    const float* W_end        = (const float*)d_in[5];
    const float* b_end        = (const float*)d_in[6];
    const float* w_score      = (const float*)d_in[7];
    const float* b_score      = (const float*)d_in[8];
    float* out = (float*)d_out;
    float* ws  = (float*)d_ws;

    float* hs     = ws;                         // 2048*512
    float* he     = hs + (BB*TT)*HH;            // 2048*512
    float* scores = he + (BB*TT)*HH;            // 8*32896
    int*   top_idx = (int*)(scores + BB*NSPANS);// 8*512

    dim3 gg(HH/64, (BB*TT)/64, 2);
    gemm_proj<<<gg, 256, 0, stream>>>(inputs, W_start, b_start, W_end, b_end, hs, he);
    span_scores<<<BB*TT, 256, 0, stream>>>(hs, he, w_score, b_score, input_mask, scores);
    topk_select<<<BB, 1024, 0, stream>>>(scores, top_idx);
    finalize<<<1, 1024, 0, stream>>>(scores, top_idx, answer_spans, out);
}

// Round 2
// 207.060 us; speedup vs baseline: 1.1404x; 1.1404x over previous
//
#include <hip/hip_runtime.h>
#include <hip/hip_bf16.h>
#include <math.h>

#define BB 8
#define TT 256
#define DD 1024
#define HH 512
#define NSPANS 32896   // T*(T+1)/2
#define KK 512
#define NEGV -1e20f
#define NCH 32
#define CHSZ 1028      // NSPANS / NCH

// ---------------------------------------------------------------------------
// Kernel 1: hs = X @ W_start + b_start ; he = X @ W_end + b_end
// ---------------------------------------------------------------------------
__global__ __launch_bounds__(256) void gemm_proj(
    const float* __restrict__ X,
    const float* __restrict__ Ws, const float* __restrict__ bs,
    const float* __restrict__ We, const float* __restrict__ be,
    float* __restrict__ hs, float* __restrict__ he)
{
    const float* W    = blockIdx.z ? We : Ws;
    const float* bias = blockIdx.z ? be : bs;
    float*       Y    = blockIdx.z ? he : hs;

    const int m0 = blockIdx.y * 64;
    const int n0 = blockIdx.x * 64;

    __shared__ float As[16][65];
    __shared__ float Bs[16][64];

    const int tid = threadIdx.x;
    const int tx = tid & 15, ty = tid >> 4;

    float acc[4][4] = {};

    const int ka = tid & 15, ma = tid >> 4;
    const int nb = tid & 63, kb = tid >> 6;

    for (int k0 = 0; k0 < DD; k0 += 16) {
        #pragma unroll
        for (int i = 0; i < 4; ++i)
            As[ka][ma + 16*i] = X[(m0 + ma + 16*i) * DD + k0 + ka];
        #pragma unroll
        for (int i = 0; i < 4; ++i)
            Bs[kb + 4*i][nb] = W[(k0 + kb + 4*i) * HH + n0 + nb];
        __syncthreads();

        #pragma unroll
        for (int k = 0; k < 16; ++k) {
            float a[4], bb[4];
            #pragma unroll
            for (int i = 0; i < 4; ++i) a[i]  = As[k][ty*4 + i];
            #pragma unroll
            for (int j = 0; j < 4; ++j) bb[j] = Bs[k][tx*4 + j];
            #pragma unroll
            for (int i = 0; i < 4; ++i)
                #pragma unroll
                for (int j = 0; j < 4; ++j)
                    acc[i][j] += a[i] * bb[j];
        }
        __syncthreads();
    }

    #pragma unroll
    for (int i = 0; i < 4; ++i) {
        const int m = m0 + ty*4 + i;
        #pragma unroll
        for (int j = 0; j < 4; ++j) {
            const int n = n0 + tx*4 + j;
            Y[m * HH + n] = acc[i][j] + bias[n];
        }
    }
}

// ---------------------------------------------------------------------------
// Kernel 2: span scores
// ---------------------------------------------------------------------------
__global__ __launch_bounds__(256) void span_scores(
    const float* __restrict__ hs, const float* __restrict__ he,
    const float* __restrict__ w_score, const float* __restrict__ b_score,
    const int* __restrict__ input_mask, float* __restrict__ scores)
{
    const int bx = blockIdx.x;
    const int b = bx >> 8;
    const int s = bx & 255;

    __shared__ float shs[HH];
    __shared__ float sw[HH];

    const int tid = threadIdx.x;
    for (int i = tid; i < HH; i += 256) {
        shs[i] = hs[(b*TT + s)*HH + i];
        sw[i]  = w_score[i];
    }
    __syncthreads();

    const int   ms  = input_mask[b*TT + s];
    const float bsc = b_score[0];
    const int wave = tid >> 6, lane = tid & 63;
    const int rowBase = s*TT - (s*(s-1))/2;

    const float4 h0 = *(const float4*)&shs[lane*8];
    const float4 h1 = *(const float4*)&shs[lane*8 + 4];
    const float4 w0 = *(const float4*)&sw[lane*8];
    const float4 w1 = *(const float4*)&sw[lane*8 + 4];

    for (int e = s + wave; e < TT; e += 4) {
        const float4* hp = (const float4*)&he[(b*TT + e)*HH];
        const float4 e0 = hp[lane*2];
        const float4 e1 = hp[lane*2 + 1];

        float p = 0.f;
        p += fmaxf(h0.x + e0.x, 0.f) * w0.x;
        p += fmaxf(h0.y + e0.y, 0.f) * w0.y;
        p += fmaxf(h0.z + e0.z, 0.f) * w0.z;
        p += fmaxf(h0.w + e0.w, 0.f) * w0.w;
        p += fmaxf(h1.x + e1.x, 0.f) * w1.x;
        p += fmaxf(h1.y + e1.y, 0.f) * w1.y;
        p += fmaxf(h1.z + e1.z, 0.f) * w1.z;
        p += fmaxf(h1.w + e1.w, 0.f) * w1.w;

        #pragma unroll
        for (int off = 32; off; off >>= 1) p += __shfl_down(p, off);

        if (lane == 0) {
            float scv = p + bsc;
            const int me = input_mask[b*TT + e];
            if (!(ms && me)) scv = NEGV;
            scores[b*NSPANS + rowBase + (e - s)] = scv;
        }
    }
}

// ---------------------------------------------------------------------------
// Parallel exact top-K pipeline
// ---------------------------------------------------------------------------
__device__ inline unsigned f2key(float f) {
    unsigned u = __float_as_uint(f);
    return u ^ ((u & 0x80000000u) ? 0xFFFFFFFFu : 0x80000000u);
}

// 3a: per-batch 16-bit histogram (global atomics), 256 blocks
__global__ __launch_bounds__(256) void hist_build(
    const float* __restrict__ scores, unsigned* __restrict__ hist16)
{
    const int b = blockIdx.x >> 5, ch = blockIdx.x & 31;
    const float* sc = scores + b*NSPANS;
    unsigned* h = hist16 + b*65536;
    const int base = ch*CHSZ;
    for (int i = base + threadIdx.x; i < base + CHSZ; i += 256)
        atomicAdd(&h[f2key(sc[i]) >> 16], 1u);
}

// 3b: per-batch find 16-bit prefix bin where cumulative-from-top crosses K
__global__ __launch_bounds__(1024) void find16(
    const unsigned* __restrict__ hist16, unsigned* __restrict__ thrInfo)
{
    const int b = blockIdx.x;
    const unsigned* h = hist16 + b*65536;
    const int tid = threadIdx.x;
    const int lane = tid & 63, wave = tid >> 6;

    const int hi = 65535 - tid*64;          // this thread's top bin (descending)
    unsigned psum = 0;
    #pragma unroll 8
    for (int j = 0; j < 64; ++j) psum += h[hi - j];

    // inclusive wave scan (thread order == descending-bin order)
    unsigned inc = psum;
    #pragma unroll
    for (int off = 1; off < 64; off <<= 1) {
        unsigned n = __shfl_up(inc, off);
        if (lane >= off) inc += n;
    }
    __shared__ unsigned wsum[16], wpre[16];
    if (lane == 63) wsum[wave] = inc;
    __syncthreads();
    if (tid == 0) { unsigned c = 0; for (int w = 0; w < 16; ++w) { wpre[w] = c; c += wsum[w]; } }
    __syncthreads();

    const unsigned before = wpre[wave] + inc - psum;   // exclusive prefix
    if (before < KK && before + psum >= KK && psum > 0) {
        unsigned cum = before;
        int bin = hi;
        for (int j = 0; j < 64; ++j) {
            const unsigned c = h[hi - j];
            if (cum + c >= KK) { bin = hi - j; break; }
            cum += c;
        }
        thrInfo[b*4 + 0] = (unsigned)bin;   // prefix16
        thrInfo[b*4 + 1] = KK - cum;        // remaining within bin
    }
}

// 3c: compact candidates (top16 == prefix16) — low 16 bits only
__global__ __launch_bounds__(256) void compact_cand(
    const float* __restrict__ scores, const unsigned* __restrict__ thrInfo,
    unsigned* __restrict__ cand, unsigned* __restrict__ candCnt)
{
    const int b = blockIdx.x >> 5, ch = blockIdx.x & 31;
    const float* sc = scores + b*NSPANS;
    const unsigned p16 = thrInfo[b*4 + 0];
    const int base = ch*CHSZ;
    for (int i = base + threadIdx.x; i < base + CHSZ; i += 256) {
        const unsigned key = f2key(sc[i]);
        if ((key >> 16) == p16) {
            const unsigned pos = atomicAdd(&candCnt[b], 1u);
            cand[b*NSPANS + pos] = key & 0xFFFFu;
        }
    }
}

// 3d: resolve exact 32-bit threshold + tiesNeeded from candidate list
__global__ __launch_bounds__(256) void refine(
    const unsigned* __restrict__ cand, const unsigned* __restrict__ candCnt,
    unsigned* __restrict__ thrInfo)
{
    const int b = blockIdx.x;
    const unsigned* cd = cand + b*NSPANS;
    const unsigned n = candCnt[b];
    const unsigned remaining = thrInfo[b*4 + 1];
    const int tid = threadIdx.x;
    __shared__ unsigned hist[256];
    __shared__ unsigned sh[2];

    hist[tid] = 0; __syncthreads();
    for (unsigned i = tid; i < n; i += 256) atomicAdd(&hist[(cd[i] >> 8) & 255u], 1u);
    __syncthreads();
    if (tid == 0) {
        unsigned cum = 0; int bin = 255;
        for (; bin > 0; --bin) { const unsigned c = hist[bin]; if (cum + c >= remaining) break; cum += c; }
        sh[0] = (unsigned)bin; sh[1] = remaining - cum;
    }
    __syncthreads();
    const unsigned b1 = sh[0], rem1 = sh[1];
    __syncthreads();

    hist[tid] = 0; __syncthreads();
    for (unsigned i = tid; i < n; i += 256) {
        const unsigned v = cd[i];
        if (((v >> 8) & 255u) == b1) atomicAdd(&hist[v & 255u], 1u);
    }
    __syncthreads();
    if (tid == 0) {
        unsigned cum = 0; int bin = 255;
        for (; bin > 0; --bin) { const unsigned c = hist[bin]; if (cum + c >= rem1) break; cum += c; }
        const unsigned thrLow = (b1 << 8) | (unsigned)bin;
        thrInfo[b*4 + 2] = (thrInfo[b*4 + 0] << 16) | thrLow;  // thr
        thrInfo[b*4 + 3] = rem1 - cum;                         // tiesNeeded
    }
}

// 3e: per-chunk counts of (key>thr), (key==thr)
__global__ __launch_bounds__(256) void countGE(
    const float* __restrict__ scores, const unsigned* __restrict__ thrInfo,
    unsigned* __restrict__ chunkCnt)
{
    const int b = blockIdx.x >> 5, ch = blockIdx.x & 31;
    const float* sc = scores + b*NSPANS;
    const unsigned thr = thrInfo[b*4 + 2];
    const int base = ch*CHSZ;
    unsigned g = 0, e = 0;
    for (int i = base + threadIdx.x; i < base + CHSZ; i += 256) {
        const unsigned key = f2key(sc[i]);
        g += (key > thr); e += (key == thr);
    }
    #pragma unroll
    for (int off = 32; off; off >>= 1) { g += __shfl_down(g, off); e += __shfl_down(e, off); }
    __shared__ unsigned sg[4], se[4];
    const int wave = threadIdx.x >> 6, lane = threadIdx.x & 63;
    if (lane == 0) { sg[wave] = g; se[wave] = e; }
    __syncthreads();
    if (threadIdx.x == 0) {
        chunkCnt[(b*NCH + ch)*2 + 0] = sg[0]+sg[1]+sg[2]+sg[3];
        chunkCnt[(b*NCH + ch)*2 + 1] = se[0]+se[1]+se[2]+se[3];
    }
}

// 3f: per-batch exclusive prefixes over chunks
__global__ __launch_bounds__(64) void scanChunks(
    const unsigned* __restrict__ chunkCnt, const unsigned* __restrict__ thrInfo,
    unsigned* __restrict__ chunkBase)
{
    const int b = blockIdx.x;
    const unsigned ties = thrInfo[b*4 + 3];
    if (threadIdx.x == 0) {
        unsigned out = 0, eqp = 0;
        for (int c = 0; c < NCH; ++c) {
            const unsigned G = chunkCnt[(b*NCH + c)*2 + 0];
            const unsigned E = chunkCnt[(b*NCH + c)*2 + 1];
            chunkBase[(b*NCH + c)*2 + 0] = out;
            chunkBase[(b*NCH + c)*2 + 1] = eqp;
            const unsigned room = (eqp >= ties) ? 0u : (ties - eqp);
            const unsigned eqTaken = (E < room) ? E : room;
            out += G + eqTaken;
            eqp += E;
        }
    }
}

// 3g: stable ordered scatter of selected indices
__global__ __launch_bounds__(256) void scatter(
    const float* __restrict__ scores, const unsigned* __restrict__ thrInfo,
    const unsigned* __restrict__ chunkBase, int* __restrict__ top_idx)
{
    const int b = blockIdx.x >> 5, ch = blockIdx.x & 31;
    const float* sc = scores + b*NSPANS;
    const unsigned thr = thrInfo[b*4 + 2], ties = thrInfo[b*4 + 3];
    unsigned outPos = chunkBase[(b*NCH + ch)*2 + 0];
    unsigned eqPos  = chunkBase[(b*NCH + ch)*2 + 1];

    const int tid = threadIdx.x, wave = tid >> 6, lane = tid & 63;
    const unsigned long long lmask = (1ull << lane) - 1ull;
    __shared__ unsigned wS[4], wE[4];

    const int base = ch*CHSZ;
    for (int seg = base; seg < base + CHSZ; seg += 256) {
        const int i = seg + tid;
        const bool valid = (i < base + CHSZ);
        const unsigned key = valid ? f2key(sc[i]) : 0u;
        const bool g  = valid && key > thr;
        const bool eq = valid && key == thr;

        const unsigned long long meq = __ballot(eq);
        if (lane == 0) wE[wave] = (unsigned)__popcll(meq);
        __syncthreads();

        unsigned eqPre = eqPos;
        for (int w = 0; w < wave; ++w) eqPre += wE[w];
        const unsigned myEqRank = eqPre + (unsigned)__popcll(meq & lmask);
        const bool sel = g || (eq && myEqRank < ties);

        const unsigned long long msel = __ballot(sel);
        if (lane == 0) wS[wave] = (unsigned)__popcll(msel);
        __syncthreads();

        unsigned selPre = outPos;
        for (int w = 0; w < wave; ++w) selPre += wS[w];
        if (sel) top_idx[b*KK + selPre + (unsigned)__popcll(msel & lmask)] = i;

        unsigned totS = 0, totE = 0;
        #pragma unroll
        for (int w = 0; w < 4; ++w) { totS += wS[w]; totE += wE[w]; }
        __syncthreads();            // all reads of wS/wE done before next write
        outPos += totS; eqPos += totE;
    }
}

// ---------------------------------------------------------------------------
// Kernel 4: finalize (probs + BCE loss), single block, deterministic
// ---------------------------------------------------------------------------
__global__ __launch_bounds__(1024) void finalize(
    const float* __restrict__ scores, const int* __restrict__ top_idx,
    const int* __restrict__ answer_spans, float* __restrict__ out)
{
    __shared__ int gold[BB*10];
    __shared__ float part[16];
    const int tid = threadIdx.x;

    if (tid < BB*10) {
        const int s0 = answer_spans[tid*2];
        const int e0 = answer_spans[tid*2 + 1];
        gold[tid] = (s0 >= 0) ? ((2*s0*TT - s0*s0 + s0)/2 + (e0 - s0)) : -1;
    }
    __syncthreads();

    float lsum = 0.f;
    for (int t = tid; t < BB*KK; t += 1024) {
        const int b = t >> 9, k = t & 511;
        const int idx = top_idx[b*KK + k];
        const float l = scores[b*NSPANS + idx];
        const float maskf = (l > -1e19f) ? 1.f : 0.f;
        float prob = 0.f;
        if (maskf != 0.f) {
            prob = 1.f / (1.f + expf(-l));
            float pred = 0.f;
            #pragma unroll
            for (int g = 0; g < 10; ++g)
                if (gold[b*10 + g] == idx) pred = 1.f;
            lsum += fmaxf(l, 0.f) - l*pred + log1pf(expf(-fabsf(l)));
        }
        out[t] = prob;
    }

    #pragma unroll
    for (int off = 32; off; off >>= 1) lsum += __shfl_down(lsum, off);
    const int wave = tid >> 6, lane = tid & 63;
    if (lane == 0) part[wave] = lsum;
    __syncthreads();
    if (tid == 0) {
        float ssum = 0.f;
        for (int w = 0; w < 16; ++w) ssum += part[w];
        out[BB*KK] = ssum;
    }
}

// ---------------------------------------------------------------------------
extern "C" void kernel_launch(void* const* d_in, const int* in_sizes, int n_in,
                              void* d_out, int out_size, void* d_ws, size_t ws_size,
                              hipStream_t stream)
{
    const float* inputs       = (const float*)d_in[0];
    const int*   input_mask   = (const int*)  d_in[1];
    const int*   answer_spans = (const int*)  d_in[2];
    const float* W_start      = (const float*)d_in[3];
    const float* b_start      = (const float*)d_in[4];
    const float* W_end        = (const float*)d_in[5];
    const float* b_end        = (const float*)d_in[6];
    const float* w_score      = (const float*)d_in[7];
    const float* b_score      = (const float*)d_in[8];
    float* out = (float*)d_out;
    unsigned* ws = (unsigned*)d_ws;

    // layout (4-byte units). cand aliases hs, hist16 aliases he (both dead
    // after span_scores).
    float*    hs       = (float*)(ws);                 // 1048576
    float*    he       = (float*)(ws + 1048576);       // 1048576
    float*    scores   = (float*)(ws + 2097152);       // 263168
    int*      top_idx  = (int*)  (ws + 2360320);       // 4096
    unsigned* candCnt  = ws + 2364416;                 // 8
    unsigned* thrInfo  = ws + 2364424;                 // 32
    unsigned* chunkCnt = ws + 2364456;                 // 512
    unsigned* chunkBase= ws + 2364968;                 // 512
    unsigned* cand     = (unsigned*)hs;                // reuse
    unsigned* hist16   = (unsigned*)he;                // reuse (8*65536)

    dim3 gg(HH/64, (BB*TT)/64, 2);
    gemm_proj<<<gg, 256, 0, stream>>>(inputs, W_start, b_start, W_end, b_end, hs, he);
    span_scores<<<BB*TT, 256, 0, stream>>>(hs, he, w_score, b_score, input_mask, scores);

    hipMemsetAsync(hist16, 0, (size_t)BB*65536*4, stream);
    hipMemsetAsync(candCnt, 0, BB*4, stream);

    hist_build  <<<BB*NCH, 256, 0, stream>>>(scores, hist16);
    find16      <<<BB, 1024, 0, stream>>>(hist16, thrInfo);
    compact_cand<<<BB*NCH, 256, 0, stream>>>(scores, thrInfo, cand, candCnt);
    refine      <<<BB, 256, 0, stream>>>(cand, candCnt, thrInfo);
    countGE     <<<BB*NCH, 256, 0, stream>>>(scores, thrInfo, chunkCnt);
    scanChunks  <<<BB, 64, 0, stream>>>(chunkCnt, thrInfo, chunkBase);
    scatter     <<<BB*NCH, 256, 0, stream>>>(scores, thrInfo, chunkBase, top_idx);

    finalize<<<1, 1024, 0, stream>>>(scores, top_idx, answer_spans, out);
}